// Round 4
// baseline (115.955 us; speedup 1.0000x reference)
//
#include <hip/hip_runtime.h>

// MarginRankingLoss over all B*B pairs.
// loss[m,n] = max(0, BIAS - 0.5*(w_m+w_n)*|p_m-p_n|)  (exact per-pair rewrite:
// the gt tie-break only affects r when diff==0, where r*diff==0 anyway).
// R1-R3 lesson: 1024x256-thread wgs + maskless full-matrix loop wins; wg count
// and kernel-node count dominate over halving the VALU work. This round keeps
// R1's hot loop and fuses the final reduction (fixed-point u64 atomics +
// last-wave-finishes), dropping the second kernel node.

#define BIAS_F 0.1f
#define FIX_SCALE 4194304.0f   // 2^22 fixed-point quantum (deterministic sum)

constexpr int TPB = 256;       // threads per block
constexpr int NPT = 8;         // n-values per thread (registers)
constexpr int TN  = TPB * NPT; // 2048 n per tile
constexpr int TM  = 32;        // m per tile

__global__ __launch_bounds__(TPB) void pair_loss_kernel(
    const float* __restrict__ pred,
    const float* __restrict__ weight,
    unsigned long long* __restrict__ acc_fix,   // d_ws[0]
    unsigned long long* __restrict__ done_cnt,  // d_ws[1]
    float* __restrict__ out,
    int B)
{
    const int n_base = blockIdx.x * TN;
    const int m_base = blockIdx.y * TM;
    const int t = threadIdx.x;

    // Per-thread n-data in registers; mask handles any n tail.
    float pn[NPT], wnh[NPT], mask[NPT];
    #pragma unroll
    for (int j = 0; j < NPT; ++j) {
        int n = n_base + j * TPB + t;
        bool ok = (n < B);
        int nc = ok ? n : 0;
        pn[j]   = pred[nc];
        wnh[j]  = weight[nc] * 0.5f;
        mask[j] = ok ? 1.0f : 0.0f;
    }

    float acc[NPT];
    #pragma unroll
    for (int j = 0; j < NPT; ++j) acc[j] = 0.0f;

    const int m_end = (m_base + TM <= B) ? TM : (B - m_base);
    #pragma unroll 8
    for (int i = 0; i < m_end; ++i) {
        const int m = m_base + i;
        const float pm  = pred[m];          // uniform -> scalar load
        const float wmh = weight[m] * 0.5f; // uniform
        #pragma unroll
        for (int j = 0; j < NPT; ++j) {
            float d  = pm - pn[j];
            float w  = wmh + wnh[j];
            float th = fmaf(-w, fabsf(d), BIAS_F); // BIAS - w*|d|
            acc[j] += fmaxf(th, 0.0f);
        }
    }

    float s = 0.0f;
    #pragma unroll
    for (int j = 0; j < NPT; ++j) s += mask[j] * acc[j];

    // wave (64-lane) reduction
    #pragma unroll
    for (int off = 32; off > 0; off >>= 1)
        s += __shfl_down(s, off, 64);

    const int lane = t & 63;
    if (lane == 0) {
        // Fixed-point: order-independent -> deterministic across replays.
        unsigned long long v = (unsigned long long)llrintf(s * FIX_SCALE);
        atomicAdd(acc_fix, v);
        __threadfence();
        const unsigned long long NW =
            (unsigned long long)gridDim.x * gridDim.y * (TPB / 64);
        unsigned long long old = atomicAdd(done_cnt, 1ULL);
        if (old == NW - 1) {
            __threadfence();
            unsigned long long total_fix = atomicAdd(acc_fix, 0ULL);
            double total = (double)total_fix * (1.0 / (double)FIX_SCALE);
            out[0] = (float)(total / ((double)B * (double)B));
        }
    }
}

extern "C" void kernel_launch(void* const* d_in, const int* in_sizes, int n_in,
                              void* d_out, int out_size, void* d_ws, size_t ws_size,
                              hipStream_t stream) {
    const float* pred   = (const float*)d_in[0];
    // d_in[1] = correct_output — mathematically irrelevant (see header comment)
    const float* weight = (const float*)d_in[2];
    float* out = (float*)d_out;
    const int B = in_sizes[0];

    unsigned long long* ws = (unsigned long long*)d_ws;
    // Zero accumulator + completion counter every call (graph-safe).
    hipMemsetAsync(ws, 0, 16, stream);

    const int tilesN = (B + TN - 1) / TN;  // 4   at B=8192
    const int tilesM = (B + TM - 1) / TM;  // 256 at B=8192
    dim3 grid(tilesN, tilesM);             // 1024 wgs — R1's winning shape
    pair_loss_kernel<<<grid, TPB, 0, stream>>>(pred, weight, ws, ws + 1, out, B);
}

// Round 5
// 17.704 us; speedup vs baseline: 6.5495x; 6.5495x over previous
//
#include <hip/hip_runtime.h>

// MarginRankingLoss over all B*B pairs.
// loss[m,n] = max(0, BIAS - 0.5*(w_m+w_n)*|p_m-p_n|)  (exact per-pair rewrite:
// the gt tie-break only affects r when diff==0, where r*diff==0 anyway).
//
// Structure = R1 champion (1024 wgs x 256 thr, full matrix, maskless hot loop,
// separate 1-wg reduce kernel). R2/R3 (more wgs / triangle) and R4 (fused
// single-address atomic reduction) all regressed — wg dispatch count and
// cross-XCD atomic/fence serialization dominate any VALU savings.
// R5 delta: thread t owns n = n_base + 8t + {0..7} (consecutive), so the
// prologue is 4x global_load_dwordx4 instead of 16 scattered scalar loads.

#define BIAS_F 0.1f

constexpr int TPB = 256;       // threads per block
constexpr int NPT = 8;         // n-values per thread (registers)
constexpr int TN  = TPB * NPT; // 2048 n per tile
constexpr int TM  = 32;        // m per tile

__global__ __launch_bounds__(TPB) void pair_loss_kernel(
    const float* __restrict__ pred,
    const float* __restrict__ weight,
    float* __restrict__ partial,
    int B)
{
    const int n_base = blockIdx.x * TN;
    const int m_base = blockIdx.y * TM;
    const int t = threadIdx.x;

    float pn[NPT], wnh[NPT], mask[NPT];

    if (n_base + TN <= B) {
        // Fast path: tile fully in range -> 4 coalesced float4 loads.
        const float4* p4 = reinterpret_cast<const float4*>(pred   + n_base) + 2 * t;
        const float4* w4 = reinterpret_cast<const float4*>(weight + n_base) + 2 * t;
        float4 pa = p4[0], pb = p4[1];
        float4 wa = w4[0], wb = w4[1];
        pn[0] = pa.x; pn[1] = pa.y; pn[2] = pa.z; pn[3] = pa.w;
        pn[4] = pb.x; pn[5] = pb.y; pn[6] = pb.z; pn[7] = pb.w;
        wnh[0] = wa.x * 0.5f; wnh[1] = wa.y * 0.5f;
        wnh[2] = wa.z * 0.5f; wnh[3] = wa.w * 0.5f;
        wnh[4] = wb.x * 0.5f; wnh[5] = wb.y * 0.5f;
        wnh[6] = wb.z * 0.5f; wnh[7] = wb.w * 0.5f;
        #pragma unroll
        for (int j = 0; j < NPT; ++j) mask[j] = 1.0f;
    } else {
        // General tail path (unused at B=8192).
        #pragma unroll
        for (int j = 0; j < NPT; ++j) {
            int n = n_base + 8 * t + j;
            bool ok = (n < B);
            int nc = ok ? n : 0;
            pn[j]   = pred[nc];
            wnh[j]  = weight[nc] * 0.5f;
            mask[j] = ok ? 1.0f : 0.0f;
        }
    }

    float acc[NPT];
    #pragma unroll
    for (int j = 0; j < NPT; ++j) acc[j] = 0.0f;

    const int m_end = (m_base + TM <= B) ? TM : (B - m_base);
    #pragma unroll 4
    for (int i = 0; i < m_end; ++i) {
        const int m = m_base + i;
        const float pm  = pred[m];          // uniform -> scalar load
        const float wmh = weight[m] * 0.5f; // uniform
        #pragma unroll
        for (int j = 0; j < NPT; ++j) {
            float d  = pm - pn[j];
            float w  = wmh + wnh[j];
            float th = fmaf(-w, fabsf(d), BIAS_F); // BIAS - w*|d|
            acc[j] += fmaxf(th, 0.0f);
        }
    }

    float s = 0.0f;
    #pragma unroll
    for (int j = 0; j < NPT; ++j) s += mask[j] * acc[j];

    // wave (64-lane) reduction
    #pragma unroll
    for (int off = 32; off > 0; off >>= 1)
        s += __shfl_down(s, off, 64);

    __shared__ float lds[TPB / 64];
    const int lane = t & 63, wid = t >> 6;
    if (lane == 0) lds[wid] = s;
    __syncthreads();
    if (t == 0) {
        float bs = 0.0f;
        #pragma unroll
        for (int w = 0; w < TPB / 64; ++w) bs += lds[w];
        partial[blockIdx.y * gridDim.x + blockIdx.x] = bs;
    }
}

__global__ __launch_bounds__(256) void reduce_kernel(
    const float* __restrict__ partial, int n, float* __restrict__ out, int B)
{
    double s = 0.0;
    for (int i = threadIdx.x; i < n; i += 256) s += (double)partial[i];
    #pragma unroll
    for (int off = 32; off > 0; off >>= 1)
        s += __shfl_down(s, off, 64);
    __shared__ double lds[4];
    const int lane = threadIdx.x & 63, wid = threadIdx.x >> 6;
    if (lane == 0) lds[wid] = s;
    __syncthreads();
    if (threadIdx.x == 0) {
        double tot = lds[0] + lds[1] + lds[2] + lds[3];
        out[0] = (float)(tot / ((double)B * (double)B));
    }
}

extern "C" void kernel_launch(void* const* d_in, const int* in_sizes, int n_in,
                              void* d_out, int out_size, void* d_ws, size_t ws_size,
                              hipStream_t stream) {
    const float* pred   = (const float*)d_in[0];
    // d_in[1] = correct_output — mathematically irrelevant (see header comment)
    const float* weight = (const float*)d_in[2];
    float* out = (float*)d_out;
    const int B = in_sizes[0];

    const int tilesN = (B + TN - 1) / TN;  // 4   at B=8192
    const int tilesM = (B + TM - 1) / TM;  // 256 at B=8192
    float* partial = (float*)d_ws;         // tilesN*tilesM floats (4 KB)

    dim3 grid(tilesN, tilesM);
    pair_loss_kernel<<<grid, TPB, 0, stream>>>(pred, weight, partial, B);
    reduce_kernel<<<1, 256, 0, stream>>>(partial, tilesN * tilesM, out, B);
}